// Round 6
// baseline (137.381 us; speedup 1.0000x reference)
//
#include <hip/hip_runtime.h>
#include <math.h>

// Problem constants (from reference)
#define BB   4
#define NN   40
#define TT   64
#define NIN  4
#define NEMB 32
#define NHID 64
#define NG   256   // 4*NHID
#define EPSW 1e-5f

__device__ __forceinline__ float fast_sigmoid(float x) {
    return __fdividef(1.0f, 1.0f + __expf(-x));
}
__device__ __forceinline__ float fast_tanh(float x) {
    return __fdividef(2.0f, 1.0f + __expf(-2.0f * x)) - 1.0f;
}
__device__ __forceinline__ float lanebcast(float v, int l) {
    return __int_as_float(__builtin_amdgcn_readlane(__float_as_int(v), l));
}

// ---------------------------------------------------------------------------
// Kernel 1: per-(b,n) LSTM chain + temporal attention pool (output cols 0..63)
// Grid: 160 blocks (b*40+n), 256 threads (one per gate row).
//
// Counter-driven history:
//  * R2: full unroll -> I-cache thrash. Loop stays ROLLED.
//  * R3-R5: VGPR_Count 44-48 across three attempts (launch_bounds, named
//    float4s, volatile-asm pins) => allocator refuses to keep the 64-float
//    W_hh row resident; re-fetches it every serial step (~1170 stall
//    cyc/step on top of ~390 VALU cyc; 1 wave/SIMD hides nothing).
//  * R6 (this): the h.W_hh dot is ONE inline-asm block; the 64 weight
//    components are "v"-constrained asm INPUTS, so they must be in VGPRs
//    at every iteration -- un-sinkable, un-spillable without reload-feeding
//    the asm, which the allocator has no reason to do at 512-VGPR budget.
//    x[t] also moves to registers (lane t holds x[t]; 4 uniform readlanes
//    per step) -- no LDS read left on the critical path except the act
//    exchange.
// ---------------------------------------------------------------------------

// one group: broadcast h[L0..L3] via readlane (imm lane), fmac into 4 chains.
// v_fmac_f32 dst,src0,vsrc1: dst += src0*vsrc1; src0 is the SGPR (1 sgpr ok).
#define DOT4(L0,L1,L2,L3, W0,W1,W2,W3)                    \
    "v_readlane_b32 %[t0], %[vh], " #L0 "\n\t"            \
    "v_readlane_b32 %[t1], %[vh], " #L1 "\n\t"            \
    "v_readlane_b32 %[t2], %[vh], " #L2 "\n\t"            \
    "v_readlane_b32 %[t3], %[vh], " #L3 "\n\t"            \
    "v_fmac_f32 %[a0], %[t0], %[" #W0 "]\n\t"             \
    "v_fmac_f32 %[a1], %[t1], %[" #W1 "]\n\t"             \
    "v_fmac_f32 %[a2], %[t2], %[" #W2 "]\n\t"             \
    "v_fmac_f32 %[a3], %[t3], %[" #W3 "]\n\t"

__global__ __launch_bounds__(256, 1)
void k_lstm(const float* __restrict__ inputs,
            const float* __restrict__ W_emb,
            const float* __restrict__ b_emb,
            const float* __restrict__ W_ih,
            const float* __restrict__ W_hh,
            const float* __restrict__ b_ih,
            const float* __restrict__ b_hh,
            const float* __restrict__ W_att,
            float* __restrict__ out,
            float* __restrict__ hs_g)
{
    __shared__ __align__(16) float s_act[2][NG];           // gate acts, double-buffered
    __shared__ __align__(16) float s_hs[TT * (NHID + 1)];  // h history, pad 65
    __shared__ __align__(16) float s_war[NHID];            // W_att[0,64:128]
    __shared__ __align__(16) float s_p[TT];                // softmax weights

    const int m   = blockIdx.x;       // b*NN + n
    const int tid = threadIdx.x;
    const int g   = tid;              // gate row 0..255
    const int j   = tid & 63;         // hidden index (= lane)
    const int gtype = g >> 6;         // 0:i 1:f 2:g 3:o (wave-uniform)

    if (tid < NHID) s_war[tid] = W_att[NHID + tid];

    // lane t of EVERY wave holds x[t] (4 floats) in registers
    const float4 xl = ((const float4*)(inputs + m * (TT * NIN)))[j];

    // ---- fold embedding into this thread's gate row: Wc[4], bc ----
    float wcx = 0.f, wcy = 0.f, wcz = 0.f, wcw = 0.f;
    float bc  = b_ih[g] + b_hh[g];
    {
        const float4* wih4  = (const float4*)(W_ih + g * NEMB);
        const float4* wemb4 = (const float4*)W_emb;   // row e (4 floats)
        #pragma unroll
        for (int e4 = 0; e4 < NEMB / 4; ++e4) {
            float4 wv = wih4[e4];
            float4 m0 = wemb4[4 * e4 + 0];
            float4 m1 = wemb4[4 * e4 + 1];
            float4 m2 = wemb4[4 * e4 + 2];
            float4 m3 = wemb4[4 * e4 + 3];
            wcx += wv.x * m0.x + wv.y * m1.x + wv.z * m2.x + wv.w * m3.x;
            wcy += wv.x * m0.y + wv.y * m1.y + wv.z * m2.y + wv.w * m3.y;
            wcz += wv.x * m0.z + wv.y * m1.z + wv.z * m2.z + wv.w * m3.z;
            wcw += wv.x * m0.w + wv.y * m1.w + wv.z * m2.w + wv.w * m3.w;
            bc  += wv.x * b_emb[4 * e4 + 0] + wv.y * b_emb[4 * e4 + 1]
                 + wv.z * b_emb[4 * e4 + 2] + wv.w * b_emb[4 * e4 + 3];
        }
    }

    // ---- recurrent weight row: 16 float4 (64 floats) ----
    const float4* q4 = (const float4*)(W_hh + g * NHID);
    const float4 w0 = q4[0],  w1 = q4[1],  w2 = q4[2],  w3 = q4[3];
    const float4 w4 = q4[4],  w5 = q4[5],  w6 = q4[6],  w7 = q4[7];
    const float4 w8 = q4[8],  w9 = q4[9],  wA = q4[10], wB = q4[11];
    const float4 wC = q4[12], wD = q4[13], wE = q4[14], wF = q4[15];

    __syncthreads();

    // ---- recurrence: 64 steps, ONE barrier each, ROLLED loop ----
    float c = 0.0f, h = 0.0f;
    #pragma unroll 1
    for (int t = 0; t < TT; ++t) {
        const int p = t & 1;

        // x-term from registers: 4 uniform readlanes + 4 FMAs
        const float xb0 = lanebcast(xl.x, t);
        const float xb1 = lanebcast(xl.y, t);
        const float xb2 = lanebcast(xl.z, t);
        const float xb3 = lanebcast(xl.w, t);
        float v0 = bc + xb0 * wcx + xb1 * wcy;
        float v1 = xb2 * wcz + xb3 * wcw;
        float v2 = 0.f, v3 = 0.f;
        float t0s, t1s, t2s, t3s;

        // h . W_hh : forced-register inline-asm dot (64 readlane + 64 fmac)
        asm(DOT4( 0, 1, 2, 3, w00,w01,w02,w03)
            DOT4( 4, 5, 6, 7, w04,w05,w06,w07)
            DOT4( 8, 9,10,11, w08,w09,w10,w11)
            DOT4(12,13,14,15, w12,w13,w14,w15)
            DOT4(16,17,18,19, w16,w17,w18,w19)
            DOT4(20,21,22,23, w20,w21,w22,w23)
            DOT4(24,25,26,27, w24,w25,w26,w27)
            DOT4(28,29,30,31, w28,w29,w30,w31)
            DOT4(32,33,34,35, w32,w33,w34,w35)
            DOT4(36,37,38,39, w36,w37,w38,w39)
            DOT4(40,41,42,43, w40,w41,w42,w43)
            DOT4(44,45,46,47, w44,w45,w46,w47)
            DOT4(48,49,50,51, w48,w49,w50,w51)
            DOT4(52,53,54,55, w52,w53,w54,w55)
            DOT4(56,57,58,59, w56,w57,w58,w59)
            DOT4(60,61,62,63, w60,w61,w62,w63)
            : [a0]"+v"(v0), [a1]"+v"(v1), [a2]"+v"(v2), [a3]"+v"(v3),
              [t0]"=&s"(t0s), [t1]"=&s"(t1s), [t2]"=&s"(t2s), [t3]"=&s"(t3s)
            : [vh]"v"(h),
              [w00]"v"(w0.x), [w01]"v"(w0.y), [w02]"v"(w0.z), [w03]"v"(w0.w),
              [w04]"v"(w1.x), [w05]"v"(w1.y), [w06]"v"(w1.z), [w07]"v"(w1.w),
              [w08]"v"(w2.x), [w09]"v"(w2.y), [w10]"v"(w2.z), [w11]"v"(w2.w),
              [w12]"v"(w3.x), [w13]"v"(w3.y), [w14]"v"(w3.z), [w15]"v"(w3.w),
              [w16]"v"(w4.x), [w17]"v"(w4.y), [w18]"v"(w4.z), [w19]"v"(w4.w),
              [w20]"v"(w5.x), [w21]"v"(w5.y), [w22]"v"(w5.z), [w23]"v"(w5.w),
              [w24]"v"(w6.x), [w25]"v"(w6.y), [w26]"v"(w6.z), [w27]"v"(w6.w),
              [w28]"v"(w7.x), [w29]"v"(w7.y), [w30]"v"(w7.z), [w31]"v"(w7.w),
              [w32]"v"(w8.x), [w33]"v"(w8.y), [w34]"v"(w8.z), [w35]"v"(w8.w),
              [w36]"v"(w9.x), [w37]"v"(w9.y), [w38]"v"(w9.z), [w39]"v"(w9.w),
              [w40]"v"(wA.x), [w41]"v"(wA.y), [w42]"v"(wA.z), [w43]"v"(wA.w),
              [w44]"v"(wB.x), [w45]"v"(wB.y), [w46]"v"(wB.z), [w47]"v"(wB.w),
              [w48]"v"(wC.x), [w49]"v"(wC.y), [w50]"v"(wC.z), [w51]"v"(wC.w),
              [w52]"v"(wD.x), [w53]"v"(wD.y), [w54]"v"(wD.z), [w55]"v"(wD.w),
              [w56]"v"(wE.x), [w57]"v"(wE.y), [w58]"v"(wE.z), [w59]"v"(wE.w),
              [w60]"v"(wF.x), [w61]"v"(wF.y), [w62]"v"(wF.z), [w63]"v"(wF.w));

        const float v = (v0 + v1) + (v2 + v3);
        const float a = (gtype == 2) ? fast_tanh(v) : fast_sigmoid(v);
        s_act[p][g] = a;
        __syncthreads();

        // redundant update in every wave (bit-identical across waves)
        const float ig = s_act[p][j];
        const float fg = s_act[p][NHID + j];
        const float gg = s_act[p][2 * NHID + j];
        const float og = s_act[p][3 * NHID + j];
        c = fg * c + ig * gg;
        h = og * fast_tanh(c);
        if (gtype == 0) s_hs[t * (NHID + 1) + j] = h;   // wave 0 records history
        // no 2nd barrier: s_act double-buffered by p; h is in registers.
    }
    __syncthreads();   // s_hs complete

    // ---- dump hs to global for kernel 2 (coalesced) ----
    #pragma unroll
    for (int idx = tid; idx < TT * NHID; idx += 256) {
        const int t = idx >> 6, hh = idx & 63;
        hs_g[m * (TT * NHID) + idx] = s_hs[t * (NHID + 1) + hh];
    }

    // ---- temporal attention pooling (softmax over t, i-independent) ----
    if (tid < TT) {
        const int t = tid;
        float r = 0.0f;
        #pragma unroll
        for (int k = 0; k < NHID; ++k)
            r += s_hs[t * (NHID + 1) + k] * s_war[k];
        float mx = r;
        #pragma unroll
        for (int off = 32; off >= 1; off >>= 1)
            mx = fmaxf(mx, __shfl_xor(mx, off));
        const float e = __expf(r - mx);
        float s = e;
        #pragma unroll
        for (int off = 32; off >= 1; off >>= 1)
            s += __shfl_xor(s, off);
        s_p[t] = __fdividef(e, s);
    }
    __syncthreads();

    if (tid < NHID) {
        float acc = 0.0f;
        #pragma unroll
        for (int t = 0; t < TT; ++t)
            acc += s_p[t] * s_hs[t * (NHID + 1) + tid];
        out[m * (2 * NHID) + tid] = fast_tanh(acc);
    }
}

// ---------------------------------------------------------------------------
// Kernel 2: spatial inverse-distance aggregation (output cols 64..127)
// chsum[b,i,h] = sum_t sum_{j!=i} hs[b,j,t,h] / (dist(i,j,t)+eps)
// Grid: 160 blocks (b*40+i), 256 threads = (t-quarter q, h).
// ---------------------------------------------------------------------------
__global__ __launch_bounds__(256)
void k_spatial(const float* __restrict__ inputs,
               const float* __restrict__ hs_g,
               float* __restrict__ out)
{
    __shared__ float s_w[TT * NN];          // 2560 inverse-distance weights
    __shared__ float s_part[4 * NHID];

    const int bi  = blockIdx.x;
    const int b   = bi / NN;
    const int i   = bi - b * NN;
    const int tid = threadIdx.x;

    for (int idx = tid; idx < TT * NN; idx += 256) {
        const int t = idx / NN;
        const int j = idx - t * NN;
        const float* pi = inputs + ((b * NN + i) * TT + t) * NIN;
        const float* pj = inputs + ((b * NN + j) * TT + t) * NIN;
        const float dx = pi[0] - pj[0];
        const float dy = pi[1] - pj[1];
        const float d  = sqrtf(dx * dx + dy * dy);
        s_w[idx] = (j == i) ? 0.0f : __fdividef(1.0f, d + EPSW);
    }
    __syncthreads();

    const int h = tid & 63;
    const int q = tid >> 6;          // t-quarter

    const float* base = hs_g + (size_t)b * NN * TT * NHID + h;
    float a0 = 0.f, a1 = 0.f, a2 = 0.f, a3 = 0.f;
    for (int t = q * 16; t < q * 16 + 16; ++t) {
        const float* hp = base + t * NHID;
        const float* wp = s_w + t * NN;
        #pragma unroll
        for (int j = 0; j < NN; j += 4) {
            a0 += wp[j + 0] * hp[(size_t)(j + 0) * TT * NHID];
            a1 += wp[j + 1] * hp[(size_t)(j + 1) * TT * NHID];
            a2 += wp[j + 2] * hp[(size_t)(j + 2) * TT * NHID];
            a3 += wp[j + 3] * hp[(size_t)(j + 3) * TT * NHID];
        }
    }
    s_part[q * NHID + h] = (a0 + a1) + (a2 + a3);
    __syncthreads();

    if (tid < NHID) {
        const float s = s_part[tid] + s_part[NHID + tid] +
                        s_part[2 * NHID + tid] + s_part[3 * NHID + tid];
        out[bi * (2 * NHID) + NHID + tid] = fast_tanh(s);
    }
}

extern "C" void kernel_launch(void* const* d_in, const int* in_sizes, int n_in,
                              void* d_out, int out_size, void* d_ws, size_t ws_size,
                              hipStream_t stream) {
    const float* inputs = (const float*)d_in[0];
    // d_in[1..4]: rel_rec / rel_send / rel_rec_t / rel_send_t (one-hot, folded)
    const float* W_emb  = (const float*)d_in[5];
    const float* b_emb  = (const float*)d_in[6];
    const float* W_ih   = (const float*)d_in[7];
    const float* W_hh   = (const float*)d_in[8];
    const float* b_ih   = (const float*)d_in[9];
    const float* b_hh   = (const float*)d_in[10];
    const float* W_att  = (const float*)d_in[11];
    // d_in[12] = b_att: cancels in the softmax, unused.

    float* outp = (float*)d_out;
    float* hs_g = (float*)d_ws;   // 160*64*64 floats = 2.62 MB

    hipLaunchKernelGGL(k_lstm, dim3(BB * NN), dim3(256), 0, stream,
                       inputs, W_emb, b_emb, W_ih, W_hh, b_ih, b_hh, W_att,
                       outp, hs_g);
    hipLaunchKernelGGL(k_spatial, dim3(BB * NN), dim3(256), 0, stream,
                       inputs, hs_g, outp);
}